// Round 1
// baseline (240.814 us; speedup 1.0000x reference)
//
#include <hip/hip_runtime.h>
#include <hip/hip_bf16.h>
#include <stdint.h>

// Problem constants
#define BB 2048
#define UU 1024
#define DD 1024
#define SKIPN 24

typedef __attribute__((ext_vector_type(8))) short short8;
typedef __attribute__((ext_vector_type(4))) float f32x4;
typedef __attribute__((ext_vector_type(4))) unsigned short ushort4_t;

static __device__ __forceinline__ float sigmoidf_(float x) {
    return 1.0f / (1.0f + __expf(-x));
}

// ---------------- transpose + f32->bf16 convert: src[R][C] -> dst[C][R] ----------
__global__ __launch_bounds__(256) void transpose_convert(
    const float* __restrict__ src, __hip_bfloat16* __restrict__ dst, int R, int C) {
    __shared__ float tile[32][33];
    const int bc = blockIdx.x * 32;
    const int br = blockIdx.y * 32;
    const int tx = threadIdx.x & 31;
    const int ty = threadIdx.x >> 5;  // 0..7
#pragma unroll
    for (int i = 0; i < 32; i += 8)
        tile[ty + i][tx] = src[(size_t)(br + ty + i) * C + bc + tx];
    __syncthreads();
#pragma unroll
    for (int i = 0; i < 32; i += 8) {
        int c = bc + ty + i;
        dst[(size_t)c * R + br + tx] = __float2bfloat16(tile[tx][ty + i]);
    }
}

// ---------------- rowwise f32->bf16 convert (strided source) ---------------------
__global__ __launch_bounds__(256) void convert_rows(
    const float* __restrict__ src, int ld, __hip_bfloat16* __restrict__ dst,
    int total4, int cols4) {
    int idx = blockIdx.x * 256 + threadIdx.x;
    if (idx >= total4) return;
    int r = idx / cols4;
    int c4 = idx - r * cols4;
    const float4 v = *(const float4*)(src + (size_t)r * ld + c4 * 4);
    union { __hip_bfloat16 h[4]; ushort4_t u; } cv;
    cv.h[0] = __float2bfloat16(v.x);
    cv.h[1] = __float2bfloat16(v.y);
    cv.h[2] = __float2bfloat16(v.z);
    cv.h[3] = __float2bfloat16(v.w);
    *(ushort4_t*)(dst + (size_t)r * (cols4 * 4) + c4 * 4) = cv.u;
}

// ---------------- fused 5-GEMM + LSTM epilogue ----------------------------------
static __device__ __forceinline__ void load_lds16(const void* g, void* l) {
    __builtin_amdgcn_global_load_lds((const __attribute__((address_space(1))) void*)g,
                                     (__attribute__((address_space(3))) void*)l, 16, 0, 0);
}

__global__ __launch_bounds__(256) void gemm_fused(
    const __hip_bfloat16* __restrict__ xin_bf,  // [B,1024]
    const __hip_bfloat16* __restrict__ h_bf,    // [B,4096]
    const __hip_bfloat16* __restrict__ ph0_bf,  // [B,1024]
    const __hip_bfloat16* __restrict__ kt,      // [4096,1024]  (kernel^T)
    const __hip_bfloat16* __restrict__ rkt,     // [4096,1024]  (recurrent_kernel^T)
    const __hip_bfloat16* __restrict__ k2t,     // [1024,1024]  (kernel2^T)
    const float* __restrict__ c_tm1,
    const float* __restrict__ bias,   // [4096]
    const float* __restrict__ bias2,  // [1024]
    const float* __restrict__ s0p,
    float* __restrict__ out_h, float* __restrict__ out_ht, float* __restrict__ out_c) {
    __shared__ short As[64 * 32];
    __shared__ short Bs[64 * 32];

    const int tid = threadIdx.x;
    const int lane = tid & 63;
    const int wid = tid >> 6;          // 0..3
    const int wrow = wid >> 1;         // 0..1
    const int wcol = wid & 1;          // 0..1
    const int v0 = blockIdx.x * 64;    // output col tile (units)
    const int b0 = blockIdx.y * 64;    // output row tile (batch)

    f32x4 acc[5][2][2];
#pragma unroll
    for (int g = 0; g < 5; g++)
#pragma unroll
        for (int m = 0; m < 2; m++)
#pragma unroll
            for (int n = 0; n < 2; n++) acc[g][m][n] = (f32x4){0.f, 0.f, 0.f, 0.f};

    // staging mapping: thread t -> LDS bytes [t*16, t*16+16) == row t>>2, slot t&3
    const int srow = tid >> 2;                   // 0..63
    const int sslot = tid & 3;                   // 0..3
    const int kofs = ((sslot ^ (srow & 3)) << 3);  // swizzled logical k offset (elems)

    char* asA = (char*)As + wid * 1024;  // per-wave uniform LDS dest
    char* asB = (char*)Bs + wid * 1024;

    const int l15 = lane & 15;
    const int hi = lane >> 4;  // 0..3
    const int ar0 = wrow * 32 + l15;
    const int ar1 = ar0 + 16;
    const int br0 = wcol * 32 + l15;
    const int br1 = br0 + 16;
    const int rsw = ((hi ^ (l15 & 3)) << 3);  // swizzled read offset (elems)

#define SEGMENT(ABASE, ALD, WBASE, G)                                             \
    {                                                                             \
        const __hip_bfloat16* Ab = (ABASE) + (size_t)(b0 + srow) * (ALD);         \
        const __hip_bfloat16* Wb = (WBASE) + (size_t)(v0 + srow) * 1024;          \
        for (int k0 = 0; k0 < 1024; k0 += 32) {                                   \
            load_lds16(Ab + k0 + kofs, asA);                                      \
            load_lds16(Wb + k0 + kofs, asB);                                      \
            __syncthreads();                                                      \
            short8 a0 = *(const short8*)(As + ar0 * 32 + rsw);                    \
            short8 a1 = *(const short8*)(As + ar1 * 32 + rsw);                    \
            short8 w0 = *(const short8*)(Bs + br0 * 32 + rsw);                    \
            short8 w1 = *(const short8*)(Bs + br1 * 32 + rsw);                    \
            acc[G][0][0] = __builtin_amdgcn_mfma_f32_16x16x32_bf16(a0, w0, acc[G][0][0], 0, 0, 0); \
            acc[G][0][1] = __builtin_amdgcn_mfma_f32_16x16x32_bf16(a0, w1, acc[G][0][1], 0, 0, 0); \
            acc[G][1][0] = __builtin_amdgcn_mfma_f32_16x16x32_bf16(a1, w0, acc[G][1][0], 0, 0, 0); \
            acc[G][1][1] = __builtin_amdgcn_mfma_f32_16x16x32_bf16(a1, w1, acc[G][1][1], 0, 0, 0); \
            __syncthreads();                                                      \
        }                                                                         \
    }

    // gate g: x-part (inputs @ kernel[:,gU:]) + r-part (h_parts[g] @ rk[:,gU:])
    SEGMENT(xin_bf, 1024, kt + (size_t)0 * 1048576, 0);
    SEGMENT(h_bf + 0 * 1024, 4096, rkt + (size_t)0 * 1048576, 0);
    SEGMENT(xin_bf, 1024, kt + (size_t)1 * 1048576, 1);
    SEGMENT(h_bf + 1 * 1024, 4096, rkt + (size_t)1 * 1048576, 1);
    SEGMENT(xin_bf, 1024, kt + (size_t)2 * 1048576, 2);
    SEGMENT(h_bf + 2 * 1024, 4096, rkt + (size_t)2 * 1048576, 2);
    SEGMENT(xin_bf, 1024, kt + (size_t)3 * 1048576, 3);
    SEGMENT(h_bf + 3 * 1024, 4096, rkt + (size_t)3 * 1048576, 3);
    SEGMENT(ph0_bf, 1024, k2t, 4);
#undef SEGMENT

    // ----- epilogue -----
    const float s0 = s0p[0];
#pragma unroll
    for (int m = 0; m < 2; m++) {
#pragma unroll
        for (int n = 0; n < 2; n++) {
            const int v = v0 + wcol * 32 + n * 16 + l15;
            const float bi = bias[v];
            const float bf_ = bias[1024 + v];
            const float bc = bias[2048 + v];
            const float bo = bias[3072 + v];
            const float b2 = bias2[v];
#pragma unroll
            for (int r = 0; r < 4; r++) {
                const int b = b0 + wrow * 32 + m * 16 + hi * 4 + r;
                const float ct = c_tm1[(size_t)b * 1024 + v];
                const float iv = sigmoidf_(acc[0][m][n][r] + bi);
                const float fv = sigmoidf_(acc[1][m][n][r] + bf_);
                const float cn = fv * ct + iv * tanhf(acc[2][m][n][r] + bc);
                const float ov = sigmoidf_(acc[3][m][n][r] + bo);
                const float sk = sigmoidf_(acc[4][m][n][r] + b2);
                const float h = s0 * (ov * tanhf(cn)) + sk * (1.0f - s0);
                out_h[(size_t)b * 1024 + v] = h;
                out_c[(size_t)b * 1024 + v] = cn;
                float* ht = out_ht + (size_t)b * 4096 + v;
                ht[0] = iv;
                ht[1024] = fv;
                ht[2048] = cn;
                ht[3072] = ov;
            }
        }
    }
}

// ---------------- shift-copy of prev_h + append h + step+1 ----------------------
__global__ __launch_bounds__(256) void copy_shift(
    const float* __restrict__ prev_h, const float* __restrict__ out_h,
    const float* __restrict__ step, float* __restrict__ out_prev,
    float* __restrict__ out_step) {
    const int C4 = (UU * SKIPN) / 4;  // 6144
    int idx = blockIdx.x * 256 + threadIdx.x;
    if (idx >= BB * C4) return;
    int b = idx / C4;
    int c4 = idx - b * C4;
    int col = c4 * 4;
    float4 v;
    if (col < UU * (SKIPN - 1))
        v = *(const float4*)(prev_h + (size_t)b * (UU * SKIPN) + col + UU);
    else
        v = *(const float4*)(out_h + (size_t)b * UU + (col - UU * (SKIPN - 1)));
    *(float4*)(out_prev + (size_t)b * (UU * SKIPN) + col) = v;
    if (idx < BB) out_step[idx] = step[idx] + 1.0f;
}

extern "C" void kernel_launch(void* const* d_in, const int* in_sizes, int n_in,
                              void* d_out, int out_size, void* d_ws, size_t ws_size,
                              hipStream_t stream) {
    (void)in_sizes; (void)n_in; (void)out_size; (void)d_ws; (void)ws_size;
    const float* inputs = (const float*)d_in[0];
    const float* h_tm1 = (const float*)d_in[1];
    const float* c_tm1 = (const float*)d_in[2];
    const float* step = (const float*)d_in[3];
    const float* prev_h = (const float*)d_in[4];
    const float* kernel = (const float*)d_in[5];
    const float* rkernel = (const float*)d_in[6];
    const float* kernel2 = (const float*)d_in[7];
    const float* bias = (const float*)d_in[8];
    const float* bias2 = (const float*)d_in[9];
    const float* s0 = (const float*)d_in[10];

    float* out = (float*)d_out;
    float* out_h = out;                    // [B,U]
    float* out_ht = out + 2097152;         // [B,4U]
    float* out_c = out + 10485760;         // [B,U]
    float* out_step = out + 12582912;      // [B,1]
    float* out_prev = out + 12584960;      // [B,U*SKIP]

    // bf16 scratch lives in the out_prev region (fully overwritten by copy_shift)
    char* scr = (char*)out_prev;
    __hip_bfloat16* kt = (__hip_bfloat16*)(scr + 0);          // [4096][1024]
    __hip_bfloat16* rkt = (__hip_bfloat16*)(scr + 8388608);   // [4096][1024]
    __hip_bfloat16* k2t = (__hip_bfloat16*)(scr + 16777216);  // [1024][1024]
    __hip_bfloat16* xin_bf = (__hip_bfloat16*)(scr + 18874368);  // [2048][1024]
    __hip_bfloat16* h_bf = (__hip_bfloat16*)(scr + 23068672);    // [2048][4096]
    __hip_bfloat16* ph0_bf = (__hip_bfloat16*)(scr + 39845888);  // [2048][1024]

    // 1) weight transpose+convert
    transpose_convert<<<dim3(4096 / 32, 1024 / 32), 256, 0, stream>>>(kernel, kt, 1024, 4096);
    transpose_convert<<<dim3(4096 / 32, 1024 / 32), 256, 0, stream>>>(rkernel, rkt, 1024, 4096);
    transpose_convert<<<dim3(1024 / 32, 1024 / 32), 256, 0, stream>>>(kernel2, k2t, 1024, 1024);

    // 2) activation converts
    convert_rows<<<(2048 * 256 + 255) / 256, 256, 0, stream>>>(inputs, 1024, xin_bf, 2048 * 256, 256);
    convert_rows<<<(2048 * 1024 + 255) / 256, 256, 0, stream>>>(h_tm1, 4096, h_bf, 2048 * 1024, 1024);
    convert_rows<<<(2048 * 256 + 255) / 256, 256, 0, stream>>>(prev_h, 24576, ph0_bf, 2048 * 256, 256);

    // 3) fused GEMMs + LSTM epilogue
    gemm_fused<<<dim3(1024 / 64, 2048 / 64), 256, 0, stream>>>(
        xin_bf, h_bf, ph0_bf, kt, rkt, k2t, c_tm1, bias, bias2, s0,
        out_h, out_ht, out_c);

    // 4) shift-copy (overwrites the scratch region) + step+1
    copy_shift<<<(2048 * 6144 + 255) / 256, 256, 0, stream>>>(prev_h, out_h, step, out_prev, out_step);
}

// Round 2
// 190.099 us; speedup vs baseline: 1.2668x; 1.2668x over previous
//
#include <hip/hip_runtime.h>
#include <hip/hip_bf16.h>
#include <stdint.h>

#define BB 2048
#define UU 1024
#define SKIPN 24

typedef __attribute__((ext_vector_type(8))) short short8;
typedef __attribute__((ext_vector_type(4))) float f32x4;
typedef __attribute__((ext_vector_type(4))) unsigned short ushort4_t;

static __device__ __forceinline__ float sigmoidf_(float x) {
    return 1.0f / (1.0f + __expf(-x));
}

static __device__ __forceinline__ void load_lds16(const void* g, void* l) {
    __builtin_amdgcn_global_load_lds((const __attribute__((address_space(1))) void*)g,
                                     (__attribute__((address_space(3))) void*)l, 16, 0, 0);
}

// ---------------- fused weight transpose + f32->bf16: src[R=1024][C] -> dst[C][1024]
__global__ __launch_bounds__(256) void transpose_all(
    const float* __restrict__ w0, const float* __restrict__ w1,
    const float* __restrict__ w2, __hip_bfloat16* __restrict__ kt,
    __hip_bfloat16* __restrict__ rkt, __hip_bfloat16* __restrict__ k2t) {
    const int z = blockIdx.z;
    const float* src = (z == 0) ? w0 : (z == 1) ? w1 : w2;
    __hip_bfloat16* dst = (z == 0) ? kt : (z == 1) ? rkt : k2t;
    const int C = (z == 2) ? 1024 : 4096;
    const int bc = blockIdx.x * 32;
    if (bc >= C) return;
    const int br = blockIdx.y * 32;
    __shared__ float tile[32][33];
    const int tx = threadIdx.x & 31;
    const int ty = threadIdx.x >> 5;  // 0..7
#pragma unroll
    for (int i = 0; i < 32; i += 8)
        tile[ty + i][tx] = src[(size_t)(br + ty + i) * C + bc + tx];
    __syncthreads();
#pragma unroll
    for (int i = 0; i < 32; i += 8)
        dst[(size_t)(bc + ty + i) * 1024 + br + tx] = __float2bfloat16(tile[tx][ty + i]);
}

// ---------------- fused activation f32->bf16 converts ---------------------------
__global__ __launch_bounds__(256) void convert_all(
    const float* __restrict__ inputs, const float* __restrict__ h_tm1,
    const float* __restrict__ prev_h, __hip_bfloat16* __restrict__ xin_bf,
    __hip_bfloat16* __restrict__ h_bf, __hip_bfloat16* __restrict__ ph0_bf) {
    const int idx = blockIdx.x * 256 + threadIdx.x;  // float4 index
    const float* src;
    __hip_bfloat16* dst;
    int off;
    if (idx < 524288) {                 // xin: 2048x1024
        src = inputs; dst = xin_bf; off = idx;
        src += (size_t)off * 4;
    } else if (idx < 2621440) {         // h: 2048x4096
        off = idx - 524288; dst = h_bf;
        src = h_tm1 + (size_t)off * 4;
    } else {                            // ph0: 2048 rows x 1024 of prev_h (ld 24576)
        const int i = idx - 2621440;
        const int b = i >> 8, c4 = i & 255;
        off = i; dst = ph0_bf;
        src = prev_h + (size_t)b * (UU * SKIPN) + c4 * 4;
    }
    const float4 v = *(const float4*)src;
    union { __hip_bfloat16 h[4]; ushort4_t u; } cv;
    cv.h[0] = __float2bfloat16(v.x);
    cv.h[1] = __float2bfloat16(v.y);
    cv.h[2] = __float2bfloat16(v.z);
    cv.h[3] = __float2bfloat16(v.w);
    *(ushort4_t*)(dst + (size_t)off * 4) = cv.u;
}

// ---------------- 128x128-tile GEMM, grid.z = gate group -----------------------
// z<4: pre[z] = inputs@kernel_z + h_part_z@rk_z   (K=2048)
// z==4: pre[4] = ph0@kernel2                       (K=1024)
__global__ __launch_bounds__(256) void gemm128(
    const __hip_bfloat16* __restrict__ xin_bf,  // [2048][1024]
    const __hip_bfloat16* __restrict__ h_bf,    // [2048][4096]
    const __hip_bfloat16* __restrict__ ph0_bf,  // [2048][1024]
    const __hip_bfloat16* __restrict__ kt,      // [4096][1024]
    const __hip_bfloat16* __restrict__ rkt,     // [4096][1024]
    const __hip_bfloat16* __restrict__ k2t,     // [1024][1024]
    float* __restrict__ pre) {                  // [5][2048][1024]
    __shared__ short As[128 * 32];
    __shared__ short Bs[128 * 32];

    const int tid = threadIdx.x;
    const int lane = tid & 63;
    const int wid = tid >> 6;        // 0..3
    const int wrow = wid >> 1;       // 0..1
    const int wcol = wid & 1;        // 0..1
    const int g = blockIdx.z;
    const int v0 = blockIdx.x * 128;
    const int b0 = blockIdx.y * 128;

    const int srow = tid >> 2;                      // 0..63
    const int sslot = tid & 3;
    const int kofs = ((sslot ^ (srow & 3)) << 3);   // swizzled k offset (elems)
    char* dA = (char*)As + wid * 1024;              // wave-uniform LDS dest
    char* dB = (char*)Bs + wid * 1024;

    const int l15 = lane & 15;
    const int hi = lane >> 4;                       // 0..3
    const int rswB = ((hi ^ (l15 & 3)) << 4);       // swizzled read offset (bytes)

    f32x4 acc[4][4];
#pragma unroll
    for (int m = 0; m < 4; m++)
#pragma unroll
        for (int n = 0; n < 4; n++) acc[m][n] = (f32x4){0.f, 0.f, 0.f, 0.f};

    const __hip_bfloat16* A1;
    const __hip_bfloat16* W1;
    const __hip_bfloat16* A2 = nullptr;
    const __hip_bfloat16* W2 = nullptr;
    int lda1;
    if (g < 4) {
        A1 = xin_bf; lda1 = 1024;
        W1 = kt + (size_t)g * 1048576;
        A2 = h_bf + (size_t)g * 1024;       // ld 4096
        W2 = rkt + (size_t)g * 1048576;
    } else {
        A1 = ph0_bf; lda1 = 1024;
        W1 = k2t;
    }

#define KSEG(AB, LDA, WB)                                                          \
    {                                                                              \
        const __hip_bfloat16* Ar0 = (AB) + (size_t)(b0 + srow) * (LDA) + kofs;     \
        const __hip_bfloat16* Ar1 = (AB) + (size_t)(b0 + 64 + srow) * (LDA) + kofs;\
        const __hip_bfloat16* Wr0 = (WB) + (size_t)(v0 + srow) * 1024 + kofs;      \
        const __hip_bfloat16* Wr1 = (WB) + (size_t)(v0 + 64 + srow) * 1024 + kofs; \
        for (int k0 = 0; k0 < 1024; k0 += 32) {                                    \
            load_lds16(Ar0 + k0, dA);                                              \
            load_lds16(Ar1 + k0, dA + 4096);                                       \
            load_lds16(Wr0 + k0, dB);                                              \
            load_lds16(Wr1 + k0, dB + 4096);                                       \
            __syncthreads();                                                       \
            short8 af[4], bf[4];                                                   \
            _Pragma("unroll")                                                      \
            for (int m = 0; m < 4; m++)                                            \
                af[m] = *(const short8*)((char*)As + (wrow * 64 + m * 16 + l15) * 64 + rswB); \
            _Pragma("unroll")                                                      \
            for (int n = 0; n < 4; n++)                                            \
                bf[n] = *(const short8*)((char*)Bs + (wcol * 64 + n * 16 + l15) * 64 + rswB); \
            _Pragma("unroll")                                                      \
            for (int m = 0; m < 4; m++)                                            \
                _Pragma("unroll")                                                  \
                for (int n = 0; n < 4; n++)                                        \
                    acc[m][n] = __builtin_amdgcn_mfma_f32_16x16x32_bf16(af[m], bf[n], acc[m][n], 0, 0, 0); \
            __syncthreads();                                                       \
        }                                                                          \
    }

    KSEG(A1, lda1, W1);
    if (g < 4) KSEG(A2, 4096, W2);
#undef KSEG

    float* P = pre + (size_t)g * 2097152;
#pragma unroll
    for (int m = 0; m < 4; m++) {
#pragma unroll
        for (int n = 0; n < 4; n++) {
            const int col = v0 + wcol * 64 + n * 16 + l15;
            const int row = b0 + wrow * 64 + m * 16 + hi * 4;
#pragma unroll
            for (int r = 0; r < 4; r++)
                P[(size_t)(row + r) * 1024 + col] = acc[m][n][r];
        }
    }
}

// ---------------- elementwise LSTM epilogue -------------------------------------
__global__ __launch_bounds__(256) void epilogue(
    const float* __restrict__ pre,   // [5][2048][1024]
    const float* __restrict__ c_tm1, const float* __restrict__ bias,
    const float* __restrict__ bias2, const float* __restrict__ s0p,
    float* __restrict__ out_h, float* __restrict__ out_ht, float* __restrict__ out_c) {
    const int idx = blockIdx.x * 256 + threadIdx.x;  // (b, v4)
    const int b = idx >> 8;
    const int v = (idx & 255) * 4;
    const size_t bv = (size_t)b * 1024 + v;
    const float4 pi = *(const float4*)(pre + bv);
    const float4 pf = *(const float4*)(pre + 2097152 + bv);
    const float4 pc = *(const float4*)(pre + 4194304 + bv);
    const float4 po = *(const float4*)(pre + 6291456 + bv);
    const float4 ps = *(const float4*)(pre + 8388608 + bv);
    const float4 ct = *(const float4*)(c_tm1 + bv);
    const float4 bi = *(const float4*)(bias + v);
    const float4 bf_ = *(const float4*)(bias + 1024 + v);
    const float4 bc = *(const float4*)(bias + 2048 + v);
    const float4 bo = *(const float4*)(bias + 3072 + v);
    const float4 b2 = *(const float4*)(bias2 + v);
    const float s0 = s0p[0];

    float4 hv, iv4, fv4, cn4, ov4;
#pragma unroll
    for (int j = 0; j < 4; j++) {
        const float iv = sigmoidf_(((const float*)&pi)[j] + ((const float*)&bi)[j]);
        const float fv = sigmoidf_(((const float*)&pf)[j] + ((const float*)&bf_)[j]);
        const float cn = fv * ((const float*)&ct)[j] + iv * tanhf(((const float*)&pc)[j] + ((const float*)&bc)[j]);
        const float ov = sigmoidf_(((const float*)&po)[j] + ((const float*)&bo)[j]);
        const float sk = sigmoidf_(((const float*)&ps)[j] + ((const float*)&b2)[j]);
        ((float*)&hv)[j] = s0 * (ov * tanhf(cn)) + sk * (1.0f - s0);
        ((float*)&iv4)[j] = iv;
        ((float*)&fv4)[j] = fv;
        ((float*)&cn4)[j] = cn;
        ((float*)&ov4)[j] = ov;
    }
    *(float4*)(out_h + bv) = hv;
    *(float4*)(out_c + bv) = cn4;
    float* ht = out_ht + (size_t)b * 4096 + v;
    *(float4*)(ht) = iv4;
    *(float4*)(ht + 1024) = fv4;
    *(float4*)(ht + 2048) = cn4;
    *(float4*)(ht + 3072) = ov4;
}

// ---------------- shift-copy of prev_h + append h + step+1 ----------------------
__global__ __launch_bounds__(256) void copy_shift(
    const float* __restrict__ prev_h, const float* __restrict__ out_h,
    const float* __restrict__ step, float* __restrict__ out_prev,
    float* __restrict__ out_step) {
    const int C4 = (UU * SKIPN) / 4;  // 6144
    int idx = blockIdx.x * 256 + threadIdx.x;
    if (idx >= BB * C4) return;
    int b = idx / C4;
    int c4 = idx - b * C4;
    int col = c4 * 4;
    float4 v;
    if (col < UU * (SKIPN - 1))
        v = *(const float4*)(prev_h + (size_t)b * (UU * SKIPN) + col + UU);
    else
        v = *(const float4*)(out_h + (size_t)b * UU + (col - UU * (SKIPN - 1)));
    *(float4*)(out_prev + (size_t)b * (UU * SKIPN) + col) = v;
    if (idx < BB) out_step[idx] = step[idx] + 1.0f;
}

extern "C" void kernel_launch(void* const* d_in, const int* in_sizes, int n_in,
                              void* d_out, int out_size, void* d_ws, size_t ws_size,
                              hipStream_t stream) {
    (void)in_sizes; (void)n_in; (void)out_size; (void)d_ws; (void)ws_size;
    const float* inputs = (const float*)d_in[0];
    const float* h_tm1 = (const float*)d_in[1];
    const float* c_tm1 = (const float*)d_in[2];
    const float* step = (const float*)d_in[3];
    const float* prev_h = (const float*)d_in[4];
    const float* kernel = (const float*)d_in[5];
    const float* rkernel = (const float*)d_in[6];
    const float* kernel2 = (const float*)d_in[7];
    const float* bias = (const float*)d_in[8];
    const float* bias2 = (const float*)d_in[9];
    const float* s0 = (const float*)d_in[10];

    float* out = (float*)d_out;
    float* out_h = out;                    // [B,U]
    float* out_ht = out + 2097152;         // [B,4U]
    float* out_c = out + 10485760;         // [B,U]
    float* out_step = out + 12582912;      // [B,1]
    float* out_prev = out + 12584960;      // [B,U*SKIP]

    // scratch inside out_prev region (fully overwritten by copy_shift at the end)
    char* scr = (char*)out_prev;
    __hip_bfloat16* kt = (__hip_bfloat16*)(scr + 0);             // [4096][1024] bf16
    __hip_bfloat16* rkt = (__hip_bfloat16*)(scr + 8388608);      // [4096][1024]
    __hip_bfloat16* k2t = (__hip_bfloat16*)(scr + 16777216);     // [1024][1024]
    __hip_bfloat16* xin_bf = (__hip_bfloat16*)(scr + 18874368);  // [2048][1024]
    __hip_bfloat16* h_bf = (__hip_bfloat16*)(scr + 23068672);    // [2048][4096]
    __hip_bfloat16* ph0_bf = (__hip_bfloat16*)(scr + 39845888);  // [2048][1024]
    float* pre = (float*)(scr + 44040192);                       // [5][2048][1024] f32

    transpose_all<<<dim3(128, 32, 3), 256, 0, stream>>>(kernel, rkernel, kernel2, kt, rkt, k2t);
    convert_all<<<12288, 256, 0, stream>>>(inputs, h_tm1, prev_h, xin_bf, h_bf, ph0_bf);
    gemm128<<<dim3(8, 16, 5), 256, 0, stream>>>(xin_bf, h_bf, ph0_bf, kt, rkt, k2t, pre);
    epilogue<<<2048, 256, 0, stream>>>(pre, c_tm1, bias, bias2, s0, out_h, out_ht, out_c);
    copy_shift<<<(BB * 6144 + 255) / 256, 256, 0, stream>>>(prev_h, out_h, step, out_prev, out_step);
}